// Round 6
// baseline (269.597 us; speedup 1.0000x reference)
//
#include <hip/hip_runtime.h>
#include <cstdint>
#include <cstddef>

// Problem constants (B=4, T=2048, C=1024, H=16, D=64). I/O dtype: fp32.
#define Bsz   4
#define Tsz   2048
#define Csz   1024
#define Hn    16
#define Dh    64
#define Mrows 8192        // B*T
#define KD    1024        // K dim of both GEMMs (= C)

#define NEG_BIG (-1.0e30f)   // finite mask sentinel: exp2(NEG_BIG) flushes to 0
#define SCL2  0.18033688011112042f  // (1/sqrt(64)) * log2(e): folded into Q at
// the QKV epilogue. p = exp2(s) directly; uniform 2^bias cancels in sum(pv)/sum(p).

typedef unsigned short u16;
typedef __bf16  bf16x8 __attribute__((ext_vector_type(8)));
typedef __bf16  bf16x2 __attribute__((ext_vector_type(2)));
typedef float   f32x4  __attribute__((ext_vector_type(4)));
typedef unsigned int u32x4 __attribute__((ext_vector_type(4)));

// Raw barrier + compiler memory fences on both sides (no implicit vmcnt(0)
// drain -- that drain is the structural stall of __syncthreads pipelines).
#define BARRIER() do { asm volatile("" ::: "memory");                          \
                       __builtin_amdgcn_s_barrier();                           \
                       asm volatile("" ::: "memory"); } while (0)

// Literal-immediate vmcnt dispatcher (asm needs compile-time immediates).
template<int N> __device__ __forceinline__ void vmwait() {
  if constexpr (N >= 12)     asm volatile("s_waitcnt vmcnt(12)" ::: "memory");
  else if constexpr (N == 9) asm volatile("s_waitcnt vmcnt(9)"  ::: "memory");
  else if constexpr (N == 8) asm volatile("s_waitcnt vmcnt(8)"  ::: "memory");
  else if constexpr (N == 6) asm volatile("s_waitcnt vmcnt(6)"  ::: "memory");
  else if constexpr (N == 4) asm volatile("s_waitcnt vmcnt(4)"  ::: "memory");
  else if constexpr (N == 3) asm volatile("s_waitcnt vmcnt(3)"  ::: "memory");
  else                       asm volatile("s_waitcnt vmcnt(0)"  ::: "memory");
}

__device__ __forceinline__ u16 f2bf(float f) {
  union { float f; unsigned int i; } v; v.f = f;
  unsigned int u = v.i;
  return (u16)((u + 0x7fffu + ((u >> 16) & 1u)) >> 16);   // RNE
}
// Pack two f32 -> two bf16 in one uint (low = a, high = b), RNE.
__device__ __forceinline__ unsigned int pack2bf(float a, float b) {
#if __has_builtin(__builtin_amdgcn_cvt_pk_bf16_f32)
  union { bf16x2 h; unsigned int u; } cv;
  cv.h = __builtin_amdgcn_cvt_pk_bf16_f32(a, b);
  return cv.u;
#else
  return (unsigned int)f2bf(a) | ((unsigned int)f2bf(b) << 16);
#endif
}
// Pack two f32 -> two bf16 by TRUNCATION via one v_perm_b32 (positive P only).
__device__ __forceinline__ unsigned int pack2bf_trunc(float lo, float hi) {
  return __builtin_amdgcn_perm(__builtin_bit_cast(unsigned int, hi),
                               __builtin_bit_cast(unsigned int, lo),
                               0x07060302u);
}
__device__ __forceinline__ float fast_exp2(float x) {
#if __has_builtin(__builtin_amdgcn_exp2f)
  return __builtin_amdgcn_exp2f(x);
#else
  return exp2f(x);
#endif
}

// ---------------------------------------------------------------------------
// Fused preprocessing (ONE launch): region 0 converts x to bf16; regions 1/2
// transpose+convert W_attn / W_proj.
// ---------------------------------------------------------------------------
#define CVT_BLKS  (Mrows * Csz / 4 / 256)   // 8192
#define TRA_BLKS  (48 * 16)                 // W_attn: [1024][3072] -> [3072][1024]
#define TRP_BLKS  (16 * 16)                 // W_proj: [1024][1024] -> [1024][1024]

__global__ __launch_bounds__(256)
void prep(const float* __restrict__ x, u16* __restrict__ xbf,
          const float* __restrict__ Wa, u16* __restrict__ WTa,
          const float* __restrict__ Wp, u16* __restrict__ WTp) {
  __shared__ u16 tile[64][65];
  int bid = blockIdx.x;
  const int tid = threadIdx.x;
  if (bid < CVT_BLKS) {
    const int i = bid * 256 + tid;
    const float4 v = ((const float4*)x)[i];
    uint2 o;
    o.x = pack2bf(v.x, v.y);
    o.y = pack2bf(v.z, v.w);
    ((uint2*)xbf)[i] = o;
    return;
  }
  bid -= CVT_BLKS;
  const float* in; u16* out; int cols, bx, by;
  if (bid < TRA_BLKS) {
    in = Wa; out = WTa; cols = 3 * Csz; bx = bid % 48; by = bid / 48;
  } else {
    bid -= TRA_BLKS;
    in = Wp; out = WTp; cols = Csz; bx = bid & 15; by = bid >> 4;
  }
  const int tc = bx * 64, tr = by * 64;
  const int xx = tid & 63, y0 = tid >> 6;
#pragma unroll
  for (int yy = 0; yy < 64; yy += 4) {
    int r = yy + y0;
    tile[r][xx] = f2bf(in[(size_t)(tr + r) * cols + tc + xx]);
  }
  __syncthreads();
#pragma unroll
  for (int yy = 0; yy < 64; yy += 4) {
    int r = yy + y0;
    out[(size_t)(tc + r) * Csz + tr + xx] = tile[xx][r];
  }
}

// ---------------------------------------------------------------------------
// GEMM C[M,N] = A[M,K] * BT[N,K]^T + bias[N], bf16 in, fp32 acc.
// V6: DELIVERY-WALL fix. Evidence: rounds 1/2/5 (three schedules, 0 conflicts,
// occupancy 19->30%) all pin at ~650 TF = 786 MB of per-block LDS-fill traffic
// / 10 TB/s chip-level L2+L3 delivery. Schedule-invariant => traffic-bound.
//   - 256-wide tiles cut traffic 2x (gemm<0>: 393 MB; gemm<1>: 201 MB).
//   - BK=32 shrinks a stage to (BM+BN)*32*2B, enabling a 4-STAGE LDS pipeline:
//     prefetch 3 ahead, steady-state vmcnt(3*PI) -- issue->use distance is
//     3 K-steps (~1000+ cyc), covering L2/L3 latency even at 1 block/CU
//     (round 4's 256x256 failure mode).
//   - 2 raw barriers per K-step; 4-slot XOR swizzle (LDS[r][s]=G[r][s^((r>>1)&3)],
//     0 conflicts measured); quadrant-rotated A-reads; setprio around MFMA.
//   - bijective XCD swizzle (grids 384 / 256, both % 8 == 0).
// gemm<0>: 256x256, 512 thr, 8 waves 2Mx4N (wave 128x64), LDS 128 KiB.
// gemm<1>: 256x128, 512 thr, 8 waves 4Mx2N (wave 64x64), LDS 96 KiB,
//          grid 256 blocks = exactly 1/CU (zero tail).
// MODE 0: QKV epilogue -> q/k scatter [bh][t][d]; Q PRE-SCALED by SCL2;
//         V scatter TRANSPOSED [bh][d][t] (packed 8B stores).
// MODE 1: plain epilogue -> fp32 fout[row*N + col].
// ---------------------------------------------------------------------------
template<int BM, int BN, int WM, int WN, int MODE>
__global__ __launch_bounds__((BM / WM) * (BN / WN) * 64, 2)
void gemm_bt(const u16* __restrict__ A, const u16* __restrict__ BT,
             const float* __restrict__ bias, u16* __restrict__ o0,
             u16* __restrict__ o1, u16* __restrict__ o2,
             float* __restrict__ fout, int N) {
  constexpr int NW   = (BM / WM) * (BN / WN);   // 8 waves
  constexpr int WNV  = BN / WN;                 // waves along N
  constexpr int MF_M = WM / 16;                 // 8 or 4
  constexpr int MF_N = WN / 16;                 // 4
  constexpr int AI   = (BM / NW) / 16;          // A DMA instrs / wave / stage
  constexpr int BI   = (BN / NW) / 16;          // B DMA instrs / wave / stage
  constexpr int PI   = AI + BI;                 // 4 (gemm<0>) or 3 (gemm<1>)

  __shared__ u16 lsA[4][BM * 32];   // [stage][row][32], slot-swizzled content
  __shared__ u16 lsB[4][BN * 32];
  const int tid  = threadIdx.x;
  const int lane = tid & 63;
  const int wid  = tid >> 6;
  const int wm   = wid / WNV, wn = wid % WNV;
  const int quad = lane >> 4, l15 = lane & 15;
  const int rswz = (l15 >> 1) & 3;          // read-side XOR (16B-slot units)

  // Bijective XCD-aware swizzle (grid sizes 384 / 256, both % 8 == 0).
  int bx, by;
  {
    const int nwg  = gridDim.x * gridDim.y;
    const int orig = (int)blockIdx.y * gridDim.x + (int)blockIdx.x;
    const int cpx  = nwg >> 3;
    const int swz  = (orig & 7) * cpx + (orig >> 3);
    bx = swz % gridDim.x; by = swz / gridDim.x;
  }
  const int m0 = by * BM, n0 = bx * BN;

  f32x4 acc[MF_M][MF_N];
#pragma unroll
  for (int i = 0; i < MF_M; ++i)
#pragma unroll
    for (int j = 0; j < MF_N; ++j) acc[i][j] = (f32x4){0.f, 0.f, 0.f, 0.f};

  // Staging: per stage, wave w DMAs BM/NW rows of A and BN/NW rows of B.
  // One instr = 64 lanes x 16B = 16 rows of 64B (BK=32 row). Lane l covers
  // row +(l>>2), slot l&3, with PRE-SWIZZLED source chunk (l&3)^((l>>3)&3)
  // so LDS[r][s] = G[r][s ^ ((r>>1)&3)] with a LINEAR DMA dest (rule #21).
  const int srow   = lane >> 2;
  const int schunk = (lane & 3) ^ ((lane >> 3) & 3);
  const u16* gA = A  + (size_t)(m0 + wid * (BM / NW) + srow) * KD + schunk * 8;
  const u16* gB = BT + (size_t)(n0 + wid * (BN / NW) + srow) * KD + schunk * 8;

  auto gstage = [&](int t, int bb) {
#if __has_builtin(__builtin_amdgcn_global_load_lds)
#pragma unroll
    for (int i = 0; i < AI; ++i)
      __builtin_amdgcn_global_load_lds(
          (const __attribute__((address_space(1))) void*)(gA + (size_t)i * 16 * KD + t * 32),
          (__attribute__((address_space(3))) void*)(&lsA[bb][(wid * (BM / NW) + i * 16) * 32]),
          16, 0, 0);
#pragma unroll
    for (int i = 0; i < BI; ++i)
      __builtin_amdgcn_global_load_lds(
          (const __attribute__((address_space(1))) void*)(gB + (size_t)i * 16 * KD + t * 32),
          (__attribute__((address_space(3))) void*)(&lsB[bb][(wid * (BN / NW) + i * 16) * 32]),
          16, 0, 0);
#else
#pragma unroll
    for (int cc = 0; cc < BM * 4 / (NW * 64); ++cc) {
      const int c = tid + cc * NW * 64;
      const int rr = c >> 2, off = c & 3;
      const int dc = (off ^ ((rr >> 1) & 3)) << 3;
      *(uint4*)&lsA[bb][rr * 32 + dc] =
          *(const uint4*)&A[(size_t)(m0 + rr) * KD + t * 32 + off * 8];
    }
#pragma unroll
    for (int cc = 0; cc < BN * 4 / (NW * 64); ++cc) {
      const int c = tid + cc * NW * 64;
      const int rr = c >> 2, off = c & 3;
      const int dc = (off ^ ((rr >> 1) & 3)) << 3;
      *(uint4*)&lsB[bb][rr * 32 + dc] =
          *(const uint4*)&BT[(size_t)(n0 + rr) * KD + t * 32 + off * 8];
    }
#endif
  };

  // Fragment reads. Row = base + m*16 + l15; bases are multiples of 16, so
  // (row>>1)&3 swizzle term = ((l15)>>1)&3 = rswz for every fragment.
#define READ_B(n_) (*(const bf16x8*)                                           \
    &lsB[cur][(wn * WN + (n_) * 16 + l15) * 32 + ((quad ^ rswz) << 3)])
#define READ_A(m_) (*(const bf16x8*)                                           \
    &lsA[cur][(wm * WM + (m_) * 16 + l15) * 32 + ((quad ^ rswz) << 3)])

  // 4-stage pipeline prologue: stages 0..2 in flight (3*PI outstanding).
  gstage(0, 0); gstage(1, 1); gstage(2, 2);
  const int KT = KD / 32;   // 32
  for (int t = 0; t < KT; ++t) {
    const int cur = t & 3;
    if (t + 3 < KT) {
      gstage(t + 3, (t + 3) & 3);   // into stage-(t-1)'s buffer: freed by the
                                    // end-of-iter barrier of iteration t-1
      vmwait<3 * PI>();             // own ledger: 4*PI out -> oldest PI (stage
                                    // t) landed; 3 stages stay in flight
    } else if (t == KT - 3) vmwait<2 * PI>();
    else if (t == KT - 2)   vmwait<PI>();
    else                    vmwait<0>();
    BARRIER();   // every wave's stage-t slice landed -> buf[cur] complete

    bf16x8 bfv[MF_N];
#pragma unroll
    for (int n = 0; n < MF_N; ++n) bfv[n] = READ_B(n);
    bf16x8 ar0 = READ_A(0);
    bf16x8 ar1 = READ_A(1);
#pragma unroll
    for (int m = 0; m < MF_M; ++m) {
      const bf16x8 am = (m & 1) ? ar1 : ar0;
      if (m + 2 < MF_M) {               // rotate: prefetch row m+2 (static idx)
        if (m & 1) ar1 = READ_A(m + 2); else ar0 = READ_A(m + 2);
      }
      __builtin_amdgcn_s_setprio(1);
#pragma unroll
      for (int n = 0; n < MF_N; ++n)
        acc[m][n] = __builtin_amdgcn_mfma_f32_16x16x32_bf16(
            am, bfv[n], acc[m][n], 0, 0, 0);
      __builtin_amdgcn_s_setprio(0);
    }

    BARRIER();   // all reads of buf[cur] done: stage t+4 may overwrite it
  }
#undef READ_B
#undef READ_A

  // Epilogue. C/D layout: col = lane&15, row = quad*4 + r (verified m89/m91).
#pragma unroll
  for (int i = 0; i < MF_M; ++i) {
#pragma unroll
    for (int j = 0; j < MF_N; ++j) {
      const int colb = n0 + wn * WN + j * 16 + l15;
      const float bv = bias[colb];
      float vals[4];
#pragma unroll
      for (int r = 0; r < 4; ++r) vals[r] = acc[i][j][r] + bv;
      const int row0 = m0 + wm * WM + i * 16 + quad * 4;
      if (MODE == 0) {
        const int b = row0 >> 11, t0 = row0 & (Tsz - 1);
        const int region = colb >> 10;        // 0:q 1:k 2:v (block-uniform)
        const int nc = colb & (Csz - 1);
        const int h = nc >> 6, d = nc & 63;
        if (region == 2) {
          // V transposed: [bh][d][t]; 4 consecutive t -> one 8B store.
          uint2 st;
          st.x = pack2bf(vals[0], vals[1]);
          st.y = pack2bf(vals[2], vals[3]);
          *(uint2*)&o2[((size_t)((b << 4) + h) * Dh + d) * Tsz + t0] = st;
        } else {
          u16* dst = (region == 0) ? o0 : o1;
          const float qs = (region == 0) ? SCL2 : 1.0f;  // fold softmax scale
#pragma unroll
          for (int r = 0; r < 4; ++r)
            dst[(size_t)(((b << 4) + h) * Tsz + t0 + r) * Dh + d] =
                f2bf(vals[r] * qs);
        }
      } else {
#pragma unroll
        for (int r = 0; r < 4; ++r)
          fout[(size_t)(row0 + r) * N + colb] = vals[r];
      }
    }
  }
}

// ---------------------------------------------------------------------------
// Fused causal flash attention (frozen since round 2): static-max softmax,
// sequential paired q-tiles, XOR-swizzled LDS + global_load_lds staging,
// counted vmcnt(4) + raw barriers, setprio around MFMA.
// grid (bh=64, y=16), 256 threads; block handles jq=31-y then jq=y.
// ---------------------------------------------------------------------------
__global__ __launch_bounds__(256)
void attn_fused(const u16* __restrict__ qb, const u16* __restrict__ kbuf,
                const u16* __restrict__ vT, u16* __restrict__ outp) {
  __shared__ u16 Kl[2][64 * 64];   // [buf][key][d],  chunk-swizzled content
  __shared__ u16 Vt[2][64 * 64];   // [buf][d][key],  chunk-swizzled content
  const int tid = threadIdx.x, lane = tid & 63, w = tid >> 6;
  const int quad = lane >> 4, l15 = lane & 15;
  const int cswz = (l15 & 7) << 3;        // read-side XOR swizzle (u16 units)
  const int bh = blockIdx.x;
  const int b = bh >> 4, h = bh & 15;
  const u16* Q   = qb   + (size_t)bh * Tsz * Dh;
  const u16* Kg  = kbuf + (size_t)bh * Tsz * Dh;
  const u16* VTg = vT   + (size_t)bh * Dh * Tsz;

  const int srow   = lane >> 3;
  const int schunk = ((lane & 7) ^ srow) << 3;       // u16 offset in row
  const u16* gK0 = Kg  + (size_t)(w * 16 + srow) * Dh  + schunk;
  const u16* gV0 = VTg + (size_t)(w * 16 + srow) * Tsz + schunk;

#if __has_builtin(__builtin_amdgcn_global_load_lds)
#define STAGE(jj, bb) do {                                                     \
    const size_t kb_ = (size_t)(jj) * 64;                                      \
    _Pragma("unroll")                                                          \
    for (int i_ = 0; i_ < 2; ++i_) {                                           \
      __builtin_amdgcn_global_load_lds(                                        \
        (const __attribute__((address_space(1))) void*)(gK0 + (kb_ + (size_t)i_ * 8) * Dh), \
        (__attribute__((address_space(3))) void*)(&Kl[bb][(w * 16 + i_ * 8) * 64]), 16, 0, 0); \
      __builtin_amdgcn_global_load_lds(                                        \
        (const __attribute__((address_space(1))) void*)(gV0 + (size_t)(i_ * 8) * Tsz + kb_), \
        (__attribute__((address_space(3))) void*)(&Vt[bb][(w * 16 + i_ * 8) * 64]), 16, 0, 0); \
    }                                                                          \
  } while (0)
#else
#define STAGE(jj, bb) do {                                                     \
    const int kb_ = (jj) * 64;                                                 \
    _Pragma("unroll")                                                          \
    for (int cc_ = 0; cc_ < 2; ++cc_) {                                        \
      const int c_ = tid + cc_ * 256;                                          \
      const int rr_ = c_ >> 3, off_ = c_ & 7;                                  \
      const int dc_ = (off_ ^ (rr_ & 7)) << 3;                                 \
      *(uint4*)&Kl[bb][rr_ * 64 + dc_] =                                       \
          *(const uint4*)&Kg[(size_t)(kb_ + rr_) * Dh + off_ * 8];             \
      *(uint4*)&Vt[bb][rr_ * 64 + dc_] =                                       \
          *(const uint4*)&VTg[(size_t)rr_ * Tsz + kb_ + off_ * 8];             \
    }                                                                          \
  } while (0)
#endif

  for (int ph = 0; ph < 2; ++ph) {
    const int jq = ph ? (int)blockIdx.y : 31 - (int)blockIdx.y;

    // Q fragment (B-operand of S^T): lane holds Q[q=l15][d=quad*8+j].
    const int qrow = jq * 64 + w * 16 + l15;   // this lane's q (global row)
    const bf16x8 bq0 = *(const bf16x8*)&Q[(size_t)qrow * Dh + quad * 8];
    const bf16x8 bq1 = *(const bf16x8*)&Q[(size_t)qrow * Dh + 32 + quad * 8];

    f32x4 O[4];    // O^T: col q = l15, row d = nb*16 + quad*4 + r
#pragma unroll
    for (int nb = 0; nb < 4; ++nb) O[nb] = (f32x4){0.f, 0.f, 0.f, 0.f};
    float l_i = 0.f;               // per-lane partial sum (16 keys/lane/tile)

    STAGE(0, 0);

    for (int j = 0; j <= jq; ++j) {
      const int cur = j & 1;
      if (j < jq) {
        STAGE(j + 1, cur ^ 1);   // prefetch next tile (async DMA)
        asm volatile("s_waitcnt vmcnt(4)" ::: "memory");  // cur landed; 4 fly
      } else {
        asm volatile("s_waitcnt vmcnt(0)" ::: "memory");
      }
      BARRIER();

      const int kb = j * 64;
      const bool diag = (j == jq);
      const int tmax = diag ? (w + 1) : 4;   // 16-key sub-tiles with any work
      const u16* KT = Kl[cur];
      const u16* VL = Vt[cur];

      // S^T: A = K fragment (m=key=16t+l15, k=d=quad*8+jj), B = Q fragment.
      f32x4 S[4];
#pragma unroll
      for (int t = 0; t < 4; ++t) S[t] = (f32x4){0.f, 0.f, 0.f, 0.f};
      __builtin_amdgcn_s_setprio(1);
#pragma unroll
      for (int t = 0; t < 4; ++t) {
        if (t < tmax) {
          bf16x8 ak = *(const bf16x8*)&KT[(t * 16 + l15) * 64 + ((quad * 8) ^ cswz)];
          S[t] = __builtin_amdgcn_mfma_f32_16x16x32_bf16(ak, bq0, S[t], 0, 0, 0);
          ak = *(const bf16x8*)&KT[(t * 16 + l15) * 64 + ((quad * 8 + 32) ^ cswz)];
          S[t] = __builtin_amdgcn_mfma_f32_16x16x32_bf16(ak, bq1, S[t], 0, 0, 0);
        }
      }
      __builtin_amdgcn_s_setprio(0);

      // p = exp2(s) directly (scale pre-folded into Q); masked -> 0.
      float p[4][4];
      if (diag) {
#pragma unroll
        for (int t = 0; t < 4; ++t) {
          const int key0 = kb + t * 16 + quad * 4;
#pragma unroll
          for (int r = 0; r < 4; ++r) {
            const float sv =
                (t < tmax && key0 + r <= qrow) ? S[t][r] : NEG_BIG;
            p[t][r] = fast_exp2(sv);
            l_i += p[t][r];
          }
        }
      } else {
#pragma unroll
        for (int t = 0; t < 4; ++t)
#pragma unroll
          for (int r = 0; r < 4; ++r) {
            p[t][r] = fast_exp2(S[t][r]);
            l_i += p[t][r];
          }
      }

      // PV chunk 0 (keys 0..31 = tiles 0,1): B-frag key pi(quad*8+jj).
      u32x4 pu;
      pu[0] = pack2bf_trunc(p[0][0], p[0][1]);
      pu[1] = pack2bf_trunc(p[0][2], p[0][3]);
      pu[2] = pack2bf_trunc(p[1][0], p[1][1]);
      pu[3] = pack2bf_trunc(p[1][2], p[1][3]);
      bf16x8 pb = __builtin_bit_cast(bf16x8, pu);
      __builtin_amdgcn_s_setprio(1);
#pragma unroll
      for (int nb = 0; nb < 4; ++nb) {
        const uint2 a0 = *(const uint2*)&VL[(nb * 16 + l15) * 64 + ((quad * 4) ^ cswz)];
        const uint2 a1 = *(const uint2*)&VL[(nb * 16 + l15) * 64 + ((quad * 4 + 16) ^ cswz)];
        const u32x4 au = {a0.x, a0.y, a1.x, a1.y};
        O[nb] = __builtin_amdgcn_mfma_f32_16x16x32_bf16(
            __builtin_bit_cast(bf16x8, au), pb, O[nb], 0, 0, 0);
      }
      __builtin_amdgcn_s_setprio(0);
      if (tmax > 2) {   // PV chunk 1 (keys 32..63 = tiles 2,3)
        pu[0] = pack2bf_trunc(p[2][0], p[2][1]);
        pu[1] = pack2bf_trunc(p[2][2], p[2][3]);
        pu[2] = pack2bf_trunc(p[3][0], p[3][1]);
        pu[3] = pack2bf_trunc(p[3][2], p[3][3]);
        pb = __builtin_bit_cast(bf16x8, pu);
        __builtin_amdgcn_s_setprio(1);
#pragma unroll
        for (int nb = 0; nb < 4; ++nb) {
          const uint2 a0 = *(const uint2*)&VL[(nb * 16 + l15) * 64 + ((quad * 4 + 32) ^ cswz)];
          const uint2 a1 = *(const uint2*)&VL[(nb * 16 + l15) * 64 + ((quad * 4 + 48) ^ cswz)];
          const u32x4 au = {a0.x, a0.y, a1.x, a1.y};
          O[nb] = __builtin_amdgcn_mfma_f32_16x16x32_bf16(
              __builtin_bit_cast(bf16x8, au), pb, O[nb], 0, 0, 0);
        }
        __builtin_amdgcn_s_setprio(0);
      }
      BARRIER();   // all waves done reading buf[cur] before it is re-staged
    }

    // One cross-lane l reduction for the whole phase, then write out.
    float lt = l_i + __shfl_xor(l_i, 16, 64);
    lt += __shfl_xor(lt, 32, 64);
    const float inv = 1.0f / lt;
#pragma unroll
    for (int nb = 0; nb < 4; ++nb) {
      uint2 st;
      st.x = pack2bf(O[nb][0] * inv, O[nb][1] * inv);
      st.y = pack2bf(O[nb][2] * inv, O[nb][3] * inv);
      *(uint2*)&outp[(size_t)(b * Tsz + qrow) * Csz + h * Dh + nb * 16 + quad * 4] = st;
    }
  }
#undef STAGE
}

// ---------------------------------------------------------------------------
extern "C" void kernel_launch(void* const* d_in, const int* in_sizes, int n_in,
                              void* d_out, int out_size, void* d_ws, size_t ws_size,
                              hipStream_t stream) {
  const float* x      = (const float*)d_in[0];   // [B,T,C] fp32
  const float* W_attn = (const float*)d_in[1];   // [C,3C]  fp32
  const float* b_attn = (const float*)d_in[2];   // [3C]    fp32
  const float* W_proj = (const float*)d_in[3];   // [C,C]   fp32
  const float* b_proj = (const float*)d_in[4];   // [C]     fp32
  float* out = (float*)d_out;                    // [B,T,C] fp32

  u16* ws   = (u16*)d_ws;
  u16* xbf  = ws;                                // [B,T,C] bf16
  u16* qbuf = xbf  + (size_t)Mrows * Csz;        // [bh][t][d] (pre-scaled)
  u16* kbuf = qbuf + (size_t)Mrows * Csz;        // [bh][t][d]
  u16* vbuf = kbuf + (size_t)Mrows * Csz;        // [bh][d][t]  (transposed!)
  u16* aout = vbuf + (size_t)Mrows * Csz;        // [B,T,C] bf16
  u16* WTa  = aout + (size_t)Mrows * Csz;        // [3C][C] bf16
  u16* WTp  = WTa  + (size_t)Csz * 3 * Csz;      // [C][C]  bf16

  prep<<<CVT_BLKS + TRA_BLKS + TRP_BLKS, 256, 0, stream>>>(
      x, xbf, W_attn, WTa, W_proj, WTp);
  // 256x256 tile, 512 thr: grid 12x32 = 384 blocks (traffic 393 MB).
  gemm_bt<256, 256, 128, 64, 0><<<dim3(3 * Csz / 256, Mrows / 256),
                                  dim3(512), 0, stream>>>(
      xbf, WTa, b_attn, qbuf, kbuf, vbuf, nullptr, 3 * Csz);
  attn_fused<<<dim3(Bsz * Hn, Tsz / 128), 256, 0, stream>>>(
      qbuf, kbuf, vbuf, aout);
  // 256x128 tile, 512 thr: grid 8x32 = 256 blocks = exactly 1/CU, no tail.
  gemm_bt<256, 128, 64, 64, 1><<<dim3(Csz / 128, Mrows / 256),
                                 dim3(512), 0, stream>>>(
      aout, WTp, b_proj, nullptr, nullptr, nullptr, out, Csz);
}

// Round 7
// 248.659 us; speedup vs baseline: 1.0842x; 1.0842x over previous
//
#include <hip/hip_runtime.h>
#include <cstdint>
#include <cstddef>

// Problem constants (B=4, T=2048, C=1024, H=16, D=64). I/O dtype: fp32.
#define Bsz   4
#define Tsz   2048
#define Csz   1024
#define Hn    16
#define Dh    64
#define Mrows 8192        // B*T
#define KD    1024        // K dim of both GEMMs (= C)

#define NEG_BIG (-1.0e30f)   // finite mask sentinel: exp2(NEG_BIG) flushes to 0
#define SCL2  0.18033688011112042f  // (1/sqrt(64)) * log2(e): folded into Q at
// the QKV epilogue. p = exp2(s) directly; uniform 2^bias cancels in sum(pv)/sum(p).

typedef unsigned short u16;
typedef __bf16  bf16x8 __attribute__((ext_vector_type(8)));
typedef __bf16  bf16x2 __attribute__((ext_vector_type(2)));
typedef float   f32x4  __attribute__((ext_vector_type(4)));
typedef unsigned int u32x4 __attribute__((ext_vector_type(4)));

// Raw barrier + compiler memory fences on both sides (no implicit vmcnt(0)
// drain -- that drain is the structural stall of __syncthreads pipelines).
#define BARRIER() do { asm volatile("" ::: "memory");                          \
                       __builtin_amdgcn_s_barrier();                           \
                       asm volatile("" ::: "memory"); } while (0)

// Literal-immediate vmcnt dispatcher (asm needs compile-time immediates).
template<int N> __device__ __forceinline__ void vmwait() {
  if constexpr (N >= 8)      asm volatile("s_waitcnt vmcnt(8)"  ::: "memory");
  else if constexpr (N == 6) asm volatile("s_waitcnt vmcnt(6)"  ::: "memory");
  else if constexpr (N == 4) asm volatile("s_waitcnt vmcnt(4)"  ::: "memory");
  else if constexpr (N == 3) asm volatile("s_waitcnt vmcnt(3)"  ::: "memory");
  else                       asm volatile("s_waitcnt vmcnt(0)"  ::: "memory");
}

__device__ __forceinline__ u16 f2bf(float f) {
  union { float f; unsigned int i; } v; v.f = f;
  unsigned int u = v.i;
  return (u16)((u + 0x7fffu + ((u >> 16) & 1u)) >> 16);   // RNE
}
// Pack two f32 -> two bf16 in one uint (low = a, high = b), RNE.
__device__ __forceinline__ unsigned int pack2bf(float a, float b) {
#if __has_builtin(__builtin_amdgcn_cvt_pk_bf16_f32)
  union { bf16x2 h; unsigned int u; } cv;
  cv.h = __builtin_amdgcn_cvt_pk_bf16_f32(a, b);
  return cv.u;
#else
  return (unsigned int)f2bf(a) | ((unsigned int)f2bf(b) << 16);
#endif
}
// Pack two f32 -> two bf16 by TRUNCATION via one v_perm_b32 (positive P only).
__device__ __forceinline__ unsigned int pack2bf_trunc(float lo, float hi) {
  return __builtin_amdgcn_perm(__builtin_bit_cast(unsigned int, hi),
                               __builtin_bit_cast(unsigned int, lo),
                               0x07060302u);
}
__device__ __forceinline__ float fast_exp2(float x) {
#if __has_builtin(__builtin_amdgcn_exp2f)
  return __builtin_amdgcn_exp2f(x);
#else
  return exp2f(x);
#endif
}

// ---------------------------------------------------------------------------
// Fused preprocessing (ONE launch): region 0 converts x to bf16; regions 1/2
// transpose+convert W_attn / W_proj.
// ---------------------------------------------------------------------------
#define CVT_BLKS  (Mrows * Csz / 4 / 256)   // 8192
#define TRA_BLKS  (48 * 16)                 // W_attn: [1024][3072] -> [3072][1024]
#define TRP_BLKS  (16 * 16)                 // W_proj: [1024][1024] -> [1024][1024]

__global__ __launch_bounds__(256)
void prep(const float* __restrict__ x, u16* __restrict__ xbf,
          const float* __restrict__ Wa, u16* __restrict__ WTa,
          const float* __restrict__ Wp, u16* __restrict__ WTp) {
  __shared__ u16 tile[64][65];
  int bid = blockIdx.x;
  const int tid = threadIdx.x;
  if (bid < CVT_BLKS) {
    const int i = bid * 256 + tid;
    const float4 v = ((const float4*)x)[i];
    uint2 o;
    o.x = pack2bf(v.x, v.y);
    o.y = pack2bf(v.z, v.w);
    ((uint2*)xbf)[i] = o;
    return;
  }
  bid -= CVT_BLKS;
  const float* in; u16* out; int cols, bx, by;
  if (bid < TRA_BLKS) {
    in = Wa; out = WTa; cols = 3 * Csz; bx = bid % 48; by = bid / 48;
  } else {
    bid -= TRA_BLKS;
    in = Wp; out = WTp; cols = Csz; bx = bid & 15; by = bid >> 4;
  }
  const int tc = bx * 64, tr = by * 64;
  const int xx = tid & 63, y0 = tid >> 6;
#pragma unroll
  for (int yy = 0; yy < 64; yy += 4) {
    int r = yy + y0;
    tile[r][xx] = f2bf(in[(size_t)(tr + r) * cols + tc + xx]);
  }
  __syncthreads();
#pragma unroll
  for (int yy = 0; yy < 64; yy += 4) {
    int r = yy + y0;
    out[(size_t)(tc + r) * Csz + tr + xx] = tile[xx][r];
  }
}

// ---------------------------------------------------------------------------
// GEMM C[M,N] = A[M,K] * BT[N,K]^T + bias[N], bf16 in, fp32 acc.
// V7: round-5's PROVEN schedule (BK=32, 2-stage double-buffer, counted
// vmcnt(PI), 2 raw barriers/step, 4-slot XOR swizzle w/ pre-swizzled DMA
// source, quadrant-rotated A reads, setprio, XCD swizzle) -- parametrized so
// gemm<0> runs a 128x256 block (8 waves, wave tile still 64x64, acc/VGPR
// unchanged). Rationale: rounds 1/2/5 pin all 128x128 variants at 78+-1 us
// (660 TF, Mfma 27%) independent of schedule => steady state is pinned; the
// remaining tax is per-block prologue/epilogue amortized over only 32 K-steps
// (K=1024). 128x256 doubles FLOPs per block epilogue and cuts fill traffic
// 23% with ZERO change to the per-K-step structure. 256^2 rewrites (r3/4/6)
// all lost; this keeps the winning inner loop byte-for-byte.
// gemm<0>: <128,256,0>, 512 thr, grid 12x64=768.
// gemm<1>: <128,128,1>, 256 thr, grid  8x64=512 (round-5 config, unchanged).
// MODE 0: QKV epilogue -> q/k scatter [bh][t][d]; Q PRE-SCALED by SCL2;
//         V scatter TRANSPOSED [bh][d][t] (packed 8B stores).
// MODE 1: plain epilogue -> fp32 fout[row*N + col].
// ---------------------------------------------------------------------------
template<int BM, int BN, int MODE>
__global__ __launch_bounds__((BM / 64) * (BN / 64) * 64, 4)
void gemm_bt(const u16* __restrict__ A, const u16* __restrict__ BT,
             const float* __restrict__ bias, u16* __restrict__ o0,
             u16* __restrict__ o1, u16* __restrict__ o2,
             float* __restrict__ fout, int N) {
  constexpr int NW  = (BM / 64) * (BN / 64);   // waves (4 or 8)
  constexpr int WNV = BN / 64;                 // waves along N
  constexpr int AI  = (BM / NW) / 16;          // A DMA instrs / wave / stage
  constexpr int BI  = (BN / NW) / 16;          // B DMA instrs / wave / stage
  constexpr int PI  = AI + BI;                 // 3 (gemm<0>) or 4 (gemm<1>)

  __shared__ u16 lsA[2][BM * 32];   // [buf][row][32], slot-swizzled content
  __shared__ u16 lsB[2][BN * 32];
  const int tid  = threadIdx.x;
  const int lane = tid & 63;
  const int wid  = tid >> 6;
  const int wm   = wid / WNV, wn = wid % WNV;  // wave tile 64x64
  const int quad = lane >> 4, l15 = lane & 15;
  const int rswz = (l15 >> 1) & 3;         // read-side XOR (16B-slot units)

  // Bijective XCD-aware swizzle (grid sizes 768 / 512, both % 8 == 0).
  int bx, by;
  {
    const int nwg  = gridDim.x * gridDim.y;
    const int orig = (int)blockIdx.y * gridDim.x + (int)blockIdx.x;
    const int cpx  = nwg >> 3;
    const int swz  = (orig & 7) * cpx + (orig >> 3);
    bx = swz % gridDim.x; by = swz / gridDim.x;
  }
  const int m0 = by * BM, n0 = bx * BN;

  f32x4 acc[4][4];
#pragma unroll
  for (int i = 0; i < 4; ++i)
#pragma unroll
    for (int j = 0; j < 4; ++j) acc[i][j] = (f32x4){0.f, 0.f, 0.f, 0.f};

  // Staging: per stage, wave w DMAs BM/NW rows of A and BN/NW rows of B.
  // One instr = 64 lanes x 16B = 16 rows of 64B (BK=32 row). Lane l covers
  // row +(l>>2), slot l&3, with PRE-SWIZZLED source chunk (l&3)^((l>>3)&3)
  // so LDS[r][s] = G[r][s ^ ((r>>1)&3)] with a LINEAR DMA dest (rule #21).
  const int srow   = lane >> 2;
  const int schunk = (lane & 3) ^ ((lane >> 3) & 3);
  const u16* gA = A  + (size_t)(m0 + wid * (BM / NW) + srow) * KD + schunk * 8;
  const u16* gB = BT + (size_t)(n0 + wid * (BN / NW) + srow) * KD + schunk * 8;

  auto gstage = [&](int t, int bb) {
#if __has_builtin(__builtin_amdgcn_global_load_lds)
#pragma unroll
    for (int i = 0; i < AI; ++i)
      __builtin_amdgcn_global_load_lds(
          (const __attribute__((address_space(1))) void*)(gA + (size_t)i * 16 * KD + t * 32),
          (__attribute__((address_space(3))) void*)(&lsA[bb][(wid * (BM / NW) + i * 16) * 32]),
          16, 0, 0);
#pragma unroll
    for (int i = 0; i < BI; ++i)
      __builtin_amdgcn_global_load_lds(
          (const __attribute__((address_space(1))) void*)(gB + (size_t)i * 16 * KD + t * 32),
          (__attribute__((address_space(3))) void*)(&lsB[bb][(wid * (BN / NW) + i * 16) * 32]),
          16, 0, 0);
#else
#pragma unroll
    for (int cc = 0; cc < BM * 4 / (NW * 64); ++cc) {
      const int c = tid + cc * NW * 64;
      const int rr = c >> 2, off = c & 3;
      const int dc = (off ^ ((rr >> 1) & 3)) << 3;
      *(uint4*)&lsA[bb][rr * 32 + dc] =
          *(const uint4*)&A[(size_t)(m0 + rr) * KD + t * 32 + off * 8];
    }
#pragma unroll
    for (int cc = 0; cc < BN * 4 / (NW * 64); ++cc) {
      const int c = tid + cc * NW * 64;
      const int rr = c >> 2, off = c & 3;
      const int dc = (off ^ ((rr >> 1) & 3)) << 3;
      *(uint4*)&lsB[bb][rr * 32 + dc] =
          *(const uint4*)&BT[(size_t)(n0 + rr) * KD + t * 32 + off * 8];
    }
#endif
  };

  // Fragment reads. Row = base + m*16 + l15; bases are multiples of 16, so
  // (row>>1)&3 swizzle term = (l15>>1)&3 = rswz for every fragment.
#define READ_B(n_) (*(const bf16x8*)                                           \
    &lsB[cur][(wn * 64 + (n_) * 16 + l15) * 32 + ((quad ^ rswz) << 3)])
#define READ_A(m_) (*(const bf16x8*)                                           \
    &lsA[cur][(wm * 64 + (m_) * 16 + l15) * 32 + ((quad ^ rswz) << 3)])
#define MFMA_ROW(m_, src)                                                      \
  __builtin_amdgcn_s_setprio(1);                                               \
  _Pragma("unroll")                                                            \
  for (int n = 0; n < 4; ++n)                                                  \
    acc[m_][n] = __builtin_amdgcn_mfma_f32_16x16x32_bf16(                      \
        src, bfv[n], acc[m_][n], 0, 0, 0);                                     \
  __builtin_amdgcn_s_setprio(0);

  gstage(0, 0);
  const int KT = KD / 32;   // 32
  for (int t = 0; t < KT; ++t) {
    const int cur = t & 1;
    if (t < KT - 1) {
      gstage(t + 1, cur ^ 1);   // PI DMA for t+1 into the other buffer
      vmwait<PI>();             // own ledger: 2*PI out -> stage t landed
    } else {
      vmwait<0>();
    }
    BARRIER();   // buf[cur] globally complete; prev reads of buf[cur^1] done

    bf16x8 bfv[4];
#pragma unroll
    for (int n = 0; n < 4; ++n) bfv[n] = READ_B(n);
    bf16x8 afA = READ_A(0);
    bf16x8 afB = READ_A(1);
    MFMA_ROW(0, afA);
    afA = READ_A(2);
    MFMA_ROW(1, afB);
    afB = READ_A(3);
    MFMA_ROW(2, afA);
    MFMA_ROW(3, afB);

    BARRIER();   // all reads of buf[cur] done before iter t+1 re-stages it
  }
#undef READ_B
#undef READ_A
#undef MFMA_ROW

  // Epilogue. C/D layout: col = lane&15, row = quad*4 + r (verified m89/m91).
#pragma unroll
  for (int i = 0; i < 4; ++i) {
#pragma unroll
    for (int j = 0; j < 4; ++j) {
      const int colb = n0 + wn * 64 + j * 16 + l15;
      const float bv = bias[colb];
      float vals[4];
#pragma unroll
      for (int r = 0; r < 4; ++r) vals[r] = acc[i][j][r] + bv;
      const int row0 = m0 + wm * 64 + i * 16 + quad * 4;
      if (MODE == 0) {
        const int b = row0 >> 11, t0 = row0 & (Tsz - 1);
        const int region = colb >> 10;        // 0:q 1:k 2:v (fragment-uniform)
        const int nc = colb & (Csz - 1);
        const int h = nc >> 6, d = nc & 63;
        if (region == 2) {
          // V transposed: [bh][d][t]; 4 consecutive t -> one 8B store.
          uint2 st;
          st.x = pack2bf(vals[0], vals[1]);
          st.y = pack2bf(vals[2], vals[3]);
          *(uint2*)&o2[((size_t)((b << 4) + h) * Dh + d) * Tsz + t0] = st;
        } else {
          u16* dst = (region == 0) ? o0 : o1;
          const float qs = (region == 0) ? SCL2 : 1.0f;  // fold softmax scale
#pragma unroll
          for (int r = 0; r < 4; ++r)
            dst[(size_t)(((b << 4) + h) * Tsz + t0 + r) * Dh + d] =
                f2bf(vals[r] * qs);
        }
      } else {
#pragma unroll
        for (int r = 0; r < 4; ++r)
          fout[(size_t)(row0 + r) * N + colb] = vals[r];
      }
    }
  }
}

// ---------------------------------------------------------------------------
// Fused causal flash attention, V9: V8 + softmax row-sum moved from the VALU
// (46% busy) to the MFMA pipe (17% busy): l = sum_k P[k][q] computed by ONE
// extra MFMA per PV chunk with A = ones(16x32) -- D[m][n] = sum_k B[k][n], so
// every lane's lmf[0] accumulates the full per-q sum (masked p contribute 0).
// Deletes 16 v_add per tile-update AND the final cross-lane shuffles.
// grid (bh=64, y=16), 256 threads; block handles jq=31-y then jq=y.
// ---------------------------------------------------------------------------
__global__ __launch_bounds__(256)
void attn_fused(const u16* __restrict__ qb, const u16* __restrict__ kbuf,
                const u16* __restrict__ vT, u16* __restrict__ outp) {
  __shared__ u16 Kl[2][64 * 64];   // [buf][key][d],  chunk-swizzled content
  __shared__ u16 Vt[2][64 * 64];   // [buf][d][key],  chunk-swizzled content
  const int tid = threadIdx.x, lane = tid & 63, w = tid >> 6;
  const int quad = lane >> 4, l15 = lane & 15;
  const int cswz = (l15 & 7) << 3;        // read-side XOR swizzle (u16 units)
  const int bh = blockIdx.x;
  const int b = bh >> 4, h = bh & 15;
  const u16* Q   = qb   + (size_t)bh * Tsz * Dh;
  const u16* Kg  = kbuf + (size_t)bh * Tsz * Dh;
  const u16* VTg = vT   + (size_t)bh * Dh * Tsz;

  // bf16 1.0 x8 (A-operand of the l-summing MFMA).
  const u32x4 onesu = {0x3F803F80u, 0x3F803F80u, 0x3F803F80u, 0x3F803F80u};
  const bf16x8 ones = __builtin_bit_cast(bf16x8, onesu);

  const int srow   = lane >> 3;
  const int schunk = ((lane & 7) ^ srow) << 3;       // u16 offset in row
  const u16* gK0 = Kg  + (size_t)(w * 16 + srow) * Dh  + schunk;
  const u16* gV0 = VTg + (size_t)(w * 16 + srow) * Tsz + schunk;

#if __has_builtin(__builtin_amdgcn_global_load_lds)
#define STAGE(jj, bb) do {                                                     \
    const size_t kb_ = (size_t)(jj) * 64;                                      \
    _Pragma("unroll")                                                          \
    for (int i_ = 0; i_ < 2; ++i_) {                                           \
      __builtin_amdgcn_global_load_lds(                                        \
        (const __attribute__((address_space(1))) void*)(gK0 + (kb_ + (size_t)i_ * 8) * Dh), \
        (__attribute__((address_space(3))) void*)(&Kl[bb][(w * 16 + i_ * 8) * 64]), 16, 0, 0); \
      __builtin_amdgcn_global_load_lds(                                        \
        (const __attribute__((address_space(1))) void*)(gV0 + (size_t)(i_ * 8) * Tsz + kb_), \
        (__attribute__((address_space(3))) void*)(&Vt[bb][(w * 16 + i_ * 8) * 64]), 16, 0, 0); \
    }                                                                          \
  } while (0)
#else
#define STAGE(jj, bb) do {                                                     \
    const int kb_ = (jj) * 64;                                                 \
    _Pragma("unroll")                                                          \
    for (int cc_ = 0; cc_ < 2; ++cc_) {                                        \
      const int c_ = tid + cc_ * 256;                                          \
      const int rr_ = c_ >> 3, off_ = c_ & 7;                                  \
      const int dc_ = (off_ ^ (rr_ & 7)) << 3;                                 \
      *(uint4*)&Kl[bb][rr_ * 64 + dc_] =                                       \
          *(const uint4*)&Kg[(size_t)(kb_ + rr_) * Dh + off_ * 8];             \
      *(uint4*)&Vt[bb][rr_ * 64 + dc_] =                                       \
          *(const uint4*)&VTg[(size_t)rr_ * Tsz + kb_ + off_ * 8];             \
    }                                                                          \
  } while (0)
#endif

  for (int ph = 0; ph < 2; ++ph) {
    const int jq = ph ? (int)blockIdx.y : 31 - (int)blockIdx.y;

    // Q fragment (B-operand of S^T): lane holds Q[q=l15][d=quad*8+j].
    const int qrow = jq * 64 + w * 16 + l15;   // this lane's q (global row)
    const bf16x8 bq0 = *(const bf16x8*)&Q[(size_t)qrow * Dh + quad * 8];
    const bf16x8 bq1 = *(const bf16x8*)&Q[(size_t)qrow * Dh + 32 + quad * 8];

    f32x4 O[4];    // O^T: col q = l15, row d = nb*16 + quad*4 + r
#pragma unroll
    for (int nb = 0; nb < 4; ++nb) O[nb] = (f32x4){0.f, 0.f, 0.f, 0.f};
    f32x4 lmf = (f32x4){0.f, 0.f, 0.f, 0.f};  // lmf[0] = per-q sum of p

    STAGE(0, 0);

    for (int j = 0; j <= jq; ++j) {
      const int cur = j & 1;
      if (j < jq) {
        STAGE(j + 1, cur ^ 1);   // prefetch next tile (async DMA)
        asm volatile("s_waitcnt vmcnt(4)" ::: "memory");  // cur landed; 4 fly
      } else {
        asm volatile("s_waitcnt vmcnt(0)" ::: "memory");
      }
      BARRIER();

      const int kb = j * 64;
      const bool diag = (j == jq);
      const int tmax = diag ? (w + 1) : 4;   // 16-key sub-tiles with any work
      const u16* KT = Kl[cur];
      const u16* VL = Vt[cur];

      // S^T: A = K fragment (m=key=16t+l15, k=d=quad*8+jj), B = Q fragment.
      f32x4 S[4];
#pragma unroll
      for (int t = 0; t < 4; ++t) S[t] = (f32x4){0.f, 0.f, 0.f, 0.f};
      __builtin_amdgcn_s_setprio(1);
#pragma unroll
      for (int t = 0; t < 4; ++t) {
        if (t < tmax) {
          bf16x8 ak = *(const bf16x8*)&KT[(t * 16 + l15) * 64 + ((quad * 8) ^ cswz)];
          S[t] = __builtin_amdgcn_mfma_f32_16x16x32_bf16(ak, bq0, S[t], 0, 0, 0);
          ak = *(const bf16x8*)&KT[(t * 16 + l15) * 64 + ((quad * 8 + 32) ^ cswz)];
          S[t] = __builtin_amdgcn_mfma_f32_16x16x32_bf16(ak, bq1, S[t], 0, 0, 0);
        }
      }
      __builtin_amdgcn_s_setprio(0);

      // p = exp2(s) directly (scale pre-folded into Q); masked -> 0.
      float p[4][4];
      if (diag) {
#pragma unroll
        for (int t = 0; t < 4; ++t) {
          const int key0 = kb + t * 16 + quad * 4;
#pragma unroll
          for (int r = 0; r < 4; ++r) {
            const float sv =
                (t < tmax && key0 + r <= qrow) ? S[t][r] : NEG_BIG;
            p[t][r] = fast_exp2(sv);
          }
        }
      } else {
#pragma unroll
        for (int t = 0; t < 4; ++t)
#pragma unroll
          for (int r = 0; r < 4; ++r)
            p[t][r] = fast_exp2(S[t][r]);
      }

      // PV chunk 0 (keys 0..31 = tiles 0,1): B-frag key pi(quad*8+jj).
      u32x4 pu;
      pu[0] = pack2bf_trunc(p[0][0], p[0][1]);
      pu[1] = pack2bf_trunc(p[0][2], p[0][3]);
      pu[2] = pack2bf_trunc(p[1][0], p[1][1]);
      pu[3] = pack2bf_trunc(p[1][2], p[1][3]);
      bf16x8 pb = __builtin_bit_cast(bf16x8, pu);
      __builtin_amdgcn_s_setprio(1);
#pragma unroll
      for (int nb = 0; nb < 4; ++nb) {
        const uint2 a0 = *(const uint2*)&VL[(nb * 16 + l15) * 64 + ((quad * 4) ^ cswz)];
        const uint2 a1 = *(const uint2*)&VL[(nb * 16 + l15) * 64 + ((quad * 4 + 16) ^ cswz)];
        const u32x4 au = {a0.x, a0.y, a1.x, a1.y};
        O[nb] = __builtin_amdgcn_mfma_f32_16x16x32_bf16(
            __builtin_bit_cast(bf16x8, au), pb, O[nb], 0, 0, 0);
      }
      lmf = __builtin_amdgcn_mfma_f32_16x16x32_bf16(ones, pb, lmf, 0, 0, 0);
      __builtin_amdgcn_s_setprio(0);
      if (tmax > 2) {   // PV chunk 1 (keys 32..63 = tiles 2,3)
        pu[0] = pack2bf_trunc(p[2][0], p[2][1]);
        pu[1] = pack2bf_trunc(p[2][2], p[2][3]);
        pu[2] = pack2bf_trunc(p[3][0], p[3][1]);
        pu[3] = pack2bf_trunc(p[3][2], p[3][3]);
        pb = __builtin_bit_cast(bf16x8, pu);
        __builtin_amdgcn_s_setprio(1);
#pragma unroll
        for (int nb = 0; nb < 4; ++nb) {
          const uint2 a0 = *(const uint2*)&VL[(nb * 16 + l15) * 64 + ((quad * 4 + 32) ^ cswz)];
          const uint2 a1 = *(const uint2*)&VL[(nb * 16 + l15) * 64 + ((quad * 4 + 48) ^ cswz)];
          const u32x4 au = {a0.x, a0.y, a1.x, a1.y};
          O[nb] = __builtin_amdgcn_mfma_f32_16x16x32_bf16(
              __builtin_bit_cast(bf16x8, au), pb, O[nb], 0, 0, 0);
        }
        lmf = __builtin_amdgcn_mfma_f32_16x16x32_bf16(ones, pb, lmf, 0, 0, 0);
        __builtin_amdgcn_s_setprio(0);
      }
      BARRIER();   // all waves done reading buf[cur] before it is re-staged
    }

    // lmf[0] already holds the full per-q denominator (no cross-lane reduce).
    const float inv = 1.0f / lmf[0];
#pragma unroll
    for (int nb = 0; nb < 4; ++nb) {
      uint2 st;
      st.x = pack2bf(O[nb][0] * inv, O[nb][1] * inv);
      st.y = pack2bf(O[nb][2] * inv, O[nb][3] * inv);
      *(uint2*)&outp[(size_t)(b * Tsz + qrow) * Csz + h * Dh + nb * 16 + quad * 4] = st;
    }
  }
#undef STAGE
}

// ---------------------------------------------------------------------------
extern "C" void kernel_launch(void* const* d_in, const int* in_sizes, int n_in,
                              void* d_out, int out_size, void* d_ws, size_t ws_size,
                              hipStream_t stream) {
  const float* x      = (const float*)d_in[0];   // [B,T,C] fp32
  const float* W_attn = (const float*)d_in[1];   // [C,3C]  fp32
  const float* b_attn = (const float*)d_in[2];   // [3C]    fp32
  const float* W_proj = (const float*)d_in[3];   // [C,C]   fp32
  const float* b_proj = (const float*)d_in[4];   // [C]     fp32
  float* out = (float*)d_out;                    // [B,T,C] fp32

  u16* ws   = (u16*)d_ws;
  u16* xbf  = ws;                                // [B,T,C] bf16
  u16* qbuf = xbf  + (size_t)Mrows * Csz;        // [bh][t][d] (pre-scaled)
  u16* kbuf = qbuf + (size_t)Mrows * Csz;        // [bh][t][d]
  u16* vbuf = kbuf + (size_t)Mrows * Csz;        // [bh][d][t]  (transposed!)
  u16* aout = vbuf + (size_t)Mrows * Csz;        // [B,T,C] bf16
  u16* WTa  = aout + (size_t)Mrows * Csz;        // [3C][C] bf16
  u16* WTp  = WTa  + (size_t)Csz * 3 * Csz;      // [C][C]  bf16

  prep<<<CVT_BLKS + TRA_BLKS + TRP_BLKS, 256, 0, stream>>>(
      x, xbf, W_attn, WTa, W_proj, WTp);
  // 128x256 tile, 512 thr: grid 12x64 = 768 blocks (fill traffic -23%,
  // epilogue tax halved vs 128^2; per-K-step schedule identical to round 5).
  gemm_bt<128, 256, 0><<<dim3(3 * Csz / 256, Mrows / 128), dim3(512), 0, stream>>>(
      xbf, WTa, b_attn, qbuf, kbuf, vbuf, nullptr, 3 * Csz);
  attn_fused<<<dim3(Bsz * Hn, Tsz / 128), 256, 0, stream>>>(
      qbuf, kbuf, vbuf, aout);
  // 128x128 tile, 256 thr: grid 8x64 = 512 blocks (round-5 config).
  gemm_bt<128, 128, 1><<<dim3(Csz / 128, Mrows / 128), dim3(256), 0, stream>>>(
      aout, WTp, b_proj, nullptr, nullptr, nullptr, out, Csz);
}

// Round 8
// 245.407 us; speedup vs baseline: 1.0986x; 1.0133x over previous
//
#include <hip/hip_runtime.h>
#include <cstdint>
#include <cstddef>

// Problem constants (B=4, T=2048, C=1024, H=16, D=64). I/O dtype: fp32.
#define Bsz   4
#define Tsz   2048
#define Csz   1024
#define Hn    16
#define Dh    64
#define Mrows 8192        // B*T
#define KD    1024        // K dim of both GEMMs (= C)

#define NEG_BIG (-1.0e30f)   // finite mask sentinel: exp2(NEG_BIG) flushes to 0
#define SCL2  0.18033688011112042f  // (1/sqrt(64)) * log2(e): folded into Q at
// the QKV epilogue. p = exp2(s) directly; uniform 2^bias cancels in sum(pv)/sum(p).

typedef unsigned short u16;
typedef __bf16  bf16x8 __attribute__((ext_vector_type(8)));
typedef __bf16  bf16x2 __attribute__((ext_vector_type(2)));
typedef float   f32x4  __attribute__((ext_vector_type(4)));
typedef unsigned int u32x4 __attribute__((ext_vector_type(4)));

// Raw barrier + compiler memory fences on both sides (no implicit vmcnt(0)
// drain -- that drain is the structural stall of __syncthreads pipelines).
#define BARRIER() do { asm volatile("" ::: "memory");                          \
                       __builtin_amdgcn_s_barrier();                           \
                       asm volatile("" ::: "memory"); } while (0)

// Literal-immediate vmcnt dispatcher (asm needs compile-time immediates).
template<int N> __device__ __forceinline__ void vmwait() {
  if constexpr (N >= 8)      asm volatile("s_waitcnt vmcnt(8)"  ::: "memory");
  else if constexpr (N == 6) asm volatile("s_waitcnt vmcnt(6)"  ::: "memory");
  else if constexpr (N == 4) asm volatile("s_waitcnt vmcnt(4)"  ::: "memory");
  else if constexpr (N == 3) asm volatile("s_waitcnt vmcnt(3)"  ::: "memory");
  else                       asm volatile("s_waitcnt vmcnt(0)"  ::: "memory");
}

__device__ __forceinline__ u16 f2bf(float f) {
  union { float f; unsigned int i; } v; v.f = f;
  unsigned int u = v.i;
  return (u16)((u + 0x7fffu + ((u >> 16) & 1u)) >> 16);   // RNE
}
// Pack two f32 -> two bf16 in one uint (low = a, high = b), RNE.
__device__ __forceinline__ unsigned int pack2bf(float a, float b) {
#if __has_builtin(__builtin_amdgcn_cvt_pk_bf16_f32)
  union { bf16x2 h; unsigned int u; } cv;
  cv.h = __builtin_amdgcn_cvt_pk_bf16_f32(a, b);
  return cv.u;
#else
  return (unsigned int)f2bf(a) | ((unsigned int)f2bf(b) << 16);
#endif
}
// Pack two f32 -> two bf16 by TRUNCATION via one v_perm_b32 (positive P only).
__device__ __forceinline__ unsigned int pack2bf_trunc(float lo, float hi) {
  return __builtin_amdgcn_perm(__builtin_bit_cast(unsigned int, hi),
                               __builtin_bit_cast(unsigned int, lo),
                               0x07060302u);
}
__device__ __forceinline__ float fast_exp2(float x) {
#if __has_builtin(__builtin_amdgcn_exp2f)
  return __builtin_amdgcn_exp2f(x);
#else
  return exp2f(x);
#endif
}

// ---------------------------------------------------------------------------
// Fused preprocessing (ONE launch): region 0 converts x to bf16; regions 1/2
// transpose+convert W_attn / W_proj.
// ---------------------------------------------------------------------------
#define CVT_BLKS  (Mrows * Csz / 4 / 256)   // 8192
#define TRA_BLKS  (48 * 16)                 // W_attn: [1024][3072] -> [3072][1024]
#define TRP_BLKS  (16 * 16)                 // W_proj: [1024][1024] -> [1024][1024]

__global__ __launch_bounds__(256)
void prep(const float* __restrict__ x, u16* __restrict__ xbf,
          const float* __restrict__ Wa, u16* __restrict__ WTa,
          const float* __restrict__ Wp, u16* __restrict__ WTp) {
  __shared__ u16 tile[64][65];
  int bid = blockIdx.x;
  const int tid = threadIdx.x;
  if (bid < CVT_BLKS) {
    const int i = bid * 256 + tid;
    const float4 v = ((const float4*)x)[i];
    uint2 o;
    o.x = pack2bf(v.x, v.y);
    o.y = pack2bf(v.z, v.w);
    ((uint2*)xbf)[i] = o;
    return;
  }
  bid -= CVT_BLKS;
  const float* in; u16* out; int cols, bx, by;
  if (bid < TRA_BLKS) {
    in = Wa; out = WTa; cols = 3 * Csz; bx = bid % 48; by = bid / 48;
  } else {
    bid -= TRA_BLKS;
    in = Wp; out = WTp; cols = Csz; bx = bid & 15; by = bid >> 4;
  }
  const int tc = bx * 64, tr = by * 64;
  const int xx = tid & 63, y0 = tid >> 6;
#pragma unroll
  for (int yy = 0; yy < 64; yy += 4) {
    int r = yy + y0;
    tile[r][xx] = f2bf(in[(size_t)(tr + r) * cols + tc + xx]);
  }
  __syncthreads();
#pragma unroll
  for (int yy = 0; yy < 64; yy += 4) {
    int r = yy + y0;
    out[(size_t)(tc + r) * Csz + tr + xx] = tile[xx][r];
  }
}

// ---------------------------------------------------------------------------
// GEMM C[M,N] = A[M,K] * BT[N,K]^T + bias[N], bf16 in, fp32 acc.
// V8: round-5 geometry and inner loop (128x128, BK=32, 256 thr, 4 waves 2x2,
// 4-slot XOR swizzle w/ pre-swizzled DMA source = 0 conflicts, quadrant-
// rotated reads, setprio, XCD swizzle) but with the sync topology changed to
// a 3-STAGE ROTATION WITH ONE BARRIER PER K-STEP (was 2-stage / 2 barriers):
//   iter t: vmwait(4) [own stage-t slice landed] -> BARRIER [buf t%3 globally
//   complete AND all reads of buf (t-1)%3 done] -> issue DMA for stage t+2
//   into buf (t+2)%3 == (t-1)%3 [race-free: its readers finished before this
//   barrier] -> compute from buf t%3.
// Rationale: across 7 rounds every 128^2 variant pinned at 77-79 us while
// conflicts/occupancy/traffic/vmcnt all varied -- the one untested invariant
// is the 2-barriers-per-K-step lockstep. This deletes half the barriers and
// overlaps DMA issue with compute. LDS 48 KiB -> 3 blocks/CU (3-vs-4 blocks
// measured perf-neutral in rounds 1/5).
// MODE 0: QKV epilogue -> q/k scatter [bh][t][d]; Q PRE-SCALED by SCL2;
//         V scatter TRANSPOSED [bh][d][t] (packed 8B stores).
// MODE 1: plain epilogue -> fp32 fout[row*N + col].
// ---------------------------------------------------------------------------
template<int MODE>
__global__ __launch_bounds__(256, 3)
void gemm_bt(const u16* __restrict__ A, const u16* __restrict__ BT,
             const float* __restrict__ bias, u16* __restrict__ o0,
             u16* __restrict__ o1, u16* __restrict__ o2,
             float* __restrict__ fout, int N) {
  __shared__ u16 lsA[3][128 * 32];   // [stage][row][32], slot-swizzled content
  __shared__ u16 lsB[3][128 * 32];
  const int tid  = threadIdx.x;
  const int lane = tid & 63;
  const int wid  = tid >> 6;               // 0..3
  const int wm   = wid & 1, wn = wid >> 1; // wave tile 64x64
  const int quad = lane >> 4, l15 = lane & 15;
  const int rswz = (l15 >> 1) & 3;         // read-side XOR (16B-slot units)

  // Bijective XCD-aware swizzle (grid sizes 1536 / 512, both % 8 == 0).
  int bx, by;
  {
    const int nwg  = gridDim.x * gridDim.y;
    const int orig = (int)blockIdx.y * gridDim.x + (int)blockIdx.x;
    const int cpx  = nwg >> 3;
    const int swz  = (orig & 7) * cpx + (orig >> 3);
    bx = swz % gridDim.x; by = swz / gridDim.x;
  }
  const int m0 = by * 128, n0 = bx * 128;

  f32x4 acc[4][4];
#pragma unroll
  for (int i = 0; i < 4; ++i)
#pragma unroll
    for (int j = 0; j < 4; ++j) acc[i][j] = (f32x4){0.f, 0.f, 0.f, 0.f};

  // Staging: per K-step, wave w DMAs A rows [w*32,w*32+32) and B rows same:
  // 2 instrs each (1 instr = 64 lanes x 16B = 16 rows of 64B). Lane l covers
  // row +(l>>2), slot l&3, with PRE-SWIZZLED source chunk (l&3)^((l>>3)&3)
  // so that LDS[r][s] = G[r][s ^ ((r>>1)&3)] with a LINEAR DMA dest.
  const int srow   = lane >> 2;
  const int schunk = (lane & 3) ^ ((lane >> 3) & 3);
  const u16* gA = A  + (size_t)(m0 + wid * 32 + srow) * KD + schunk * 8;
  const u16* gB = BT + (size_t)(n0 + wid * 32 + srow) * KD + schunk * 8;

  auto gstage = [&](int t, int bb) {
#if __has_builtin(__builtin_amdgcn_global_load_lds)
#pragma unroll
    for (int i = 0; i < 2; ++i)
      __builtin_amdgcn_global_load_lds(
          (const __attribute__((address_space(1))) void*)(gA + (size_t)i * 16 * KD + t * 32),
          (__attribute__((address_space(3))) void*)(&lsA[bb][(wid * 32 + i * 16) * 32]),
          16, 0, 0);
#pragma unroll
    for (int i = 0; i < 2; ++i)
      __builtin_amdgcn_global_load_lds(
          (const __attribute__((address_space(1))) void*)(gB + (size_t)i * 16 * KD + t * 32),
          (__attribute__((address_space(3))) void*)(&lsB[bb][(wid * 32 + i * 16) * 32]),
          16, 0, 0);
#else
#pragma unroll
    for (int cc = 0; cc < 2; ++cc) {
      const int c = tid + cc * 256;
      const int rr = c >> 2, off = c & 3;
      const int dc = (off ^ ((rr >> 1) & 3)) << 3;
      *(uint4*)&lsA[bb][rr * 32 + dc] =
          *(const uint4*)&A[(size_t)(m0 + rr) * KD + t * 32 + off * 8];
    }
#pragma unroll
    for (int cc = 0; cc < 2; ++cc) {
      const int c = tid + cc * 256;
      const int rr = c >> 2, off = c & 3;
      const int dc = (off ^ ((rr >> 1) & 3)) << 3;
      *(uint4*)&lsB[bb][rr * 32 + dc] =
          *(const uint4*)&BT[(size_t)(n0 + rr) * KD + t * 32 + off * 8];
    }
#endif
  };

  // Fragment read helpers. Row within tile: base + m*16 + l15; swizzle term
  // depends only on l15 (bases contribute multiples of 8 to row>>1).
#define READ_B(n_) (*(const bf16x8*)                                           \
    &lsB[cur][(wn * 64 + (n_) * 16 + l15) * 32 + ((quad ^ rswz) << 3)])
#define READ_A(m_) (*(const bf16x8*)                                           \
    &lsA[cur][(wm * 64 + (m_) * 16 + l15) * 32 + ((quad ^ rswz) << 3)])
#define MFMA_ROW(m_, src)                                                      \
  __builtin_amdgcn_s_setprio(1);                                               \
  _Pragma("unroll")                                                            \
  for (int n = 0; n < 4; ++n)                                                  \
    acc[m_][n] = __builtin_amdgcn_mfma_f32_16x16x32_bf16(                      \
        src, bfv[n], acc[m_][n], 0, 0, 0);                                     \
  __builtin_amdgcn_s_setprio(0);

  // 3-stage prologue: stages 0 and 1 in flight (8 DMA outstanding).
  gstage(0, 0); gstage(1, 1);
  const int KT = KD / 32;   // 32
  int cur = 0;
  for (int t = 0; t < KT; ++t) {
    if (t < KT - 1) vmwait<4>();   // own ledger: 8 out -> stage t landed,
    else            vmwait<0>();   // stage t+1's 4 stay in flight
    BARRIER();   // buf[cur] globally complete; reads of buf[(t-1)%3] all done

    if (t + 2 < KT) {
      int nb2 = cur + 2; if (nb2 >= 3) nb2 -= 3;   // == (t-1)%3: freed above
      gstage(t + 2, nb2);
    }

    bf16x8 bfv[4];
#pragma unroll
    for (int n = 0; n < 4; ++n) bfv[n] = READ_B(n);
    bf16x8 afA = READ_A(0);
    bf16x8 afB = READ_A(1);
    MFMA_ROW(0, afA);
    afA = READ_A(2);
    MFMA_ROW(1, afB);
    afB = READ_A(3);
    MFMA_ROW(2, afA);
    MFMA_ROW(3, afB);

    cur = (cur == 2) ? 0 : cur + 1;   // single barrier per step: no tail sync
  }
#undef READ_B
#undef READ_A
#undef MFMA_ROW

  // Epilogue. C/D layout: col = lane&15, row = quad*4 + r (verified m89/m91).
#pragma unroll
  for (int i = 0; i < 4; ++i) {
#pragma unroll
    for (int j = 0; j < 4; ++j) {
      const int colb = n0 + wn * 64 + j * 16 + l15;
      const float bv = bias[colb];
      float vals[4];
#pragma unroll
      for (int r = 0; r < 4; ++r) vals[r] = acc[i][j][r] + bv;
      const int row0 = m0 + wm * 64 + i * 16 + quad * 4;
      if (MODE == 0) {
        const int b = row0 >> 11, t0 = row0 & (Tsz - 1);
        const int region = colb >> 10;        // 0:q 1:k 2:v (fragment-uniform)
        const int nc = colb & (Csz - 1);
        const int h = nc >> 6, d = nc & 63;
        if (region == 2) {
          // V transposed: [bh][d][t]; 4 consecutive t -> one 8B store.
          uint2 st;
          st.x = pack2bf(vals[0], vals[1]);
          st.y = pack2bf(vals[2], vals[3]);
          *(uint2*)&o2[((size_t)((b << 4) + h) * Dh + d) * Tsz + t0] = st;
        } else {
          u16* dst = (region == 0) ? o0 : o1;
          const float qs = (region == 0) ? SCL2 : 1.0f;  // fold softmax scale
#pragma unroll
          for (int r = 0; r < 4; ++r)
            dst[(size_t)(((b << 4) + h) * Tsz + t0 + r) * Dh + d] =
                f2bf(vals[r] * qs);
        }
      } else {
#pragma unroll
        for (int r = 0; r < 4; ++r)
          fout[(size_t)(row0 + r) * N + colb] = vals[r];
      }
    }
  }
}

// ---------------------------------------------------------------------------
// Fused causal flash attention (round-5 version, reverted: the round-7 MFMA
// row-sum cost ~4 us): static-max softmax, sequential paired q-tiles,
// XOR-swizzled LDS + global_load_lds staging, counted vmcnt(4) + raw
// barriers, setprio around MFMA, per-lane l_i + one cross-lane reduce.
// grid (bh=64, y=16), 256 threads; block handles jq=31-y then jq=y.
// ---------------------------------------------------------------------------
__global__ __launch_bounds__(256)
void attn_fused(const u16* __restrict__ qb, const u16* __restrict__ kbuf,
                const u16* __restrict__ vT, u16* __restrict__ outp) {
  __shared__ u16 Kl[2][64 * 64];   // [buf][key][d],  chunk-swizzled content
  __shared__ u16 Vt[2][64 * 64];   // [buf][d][key],  chunk-swizzled content
  const int tid = threadIdx.x, lane = tid & 63, w = tid >> 6;
  const int quad = lane >> 4, l15 = lane & 15;
  const int cswz = (l15 & 7) << 3;        // read-side XOR swizzle (u16 units)
  const int bh = blockIdx.x;
  const int b = bh >> 4, h = bh & 15;
  const u16* Q   = qb   + (size_t)bh * Tsz * Dh;
  const u16* Kg  = kbuf + (size_t)bh * Tsz * Dh;
  const u16* VTg = vT   + (size_t)bh * Dh * Tsz;

  const int srow   = lane >> 3;
  const int schunk = ((lane & 7) ^ srow) << 3;       // u16 offset in row
  const u16* gK0 = Kg  + (size_t)(w * 16 + srow) * Dh  + schunk;
  const u16* gV0 = VTg + (size_t)(w * 16 + srow) * Tsz + schunk;

#if __has_builtin(__builtin_amdgcn_global_load_lds)
#define STAGE(jj, bb) do {                                                     \
    const size_t kb_ = (size_t)(jj) * 64;                                      \
    _Pragma("unroll")                                                          \
    for (int i_ = 0; i_ < 2; ++i_) {                                           \
      __builtin_amdgcn_global_load_lds(                                        \
        (const __attribute__((address_space(1))) void*)(gK0 + (kb_ + (size_t)i_ * 8) * Dh), \
        (__attribute__((address_space(3))) void*)(&Kl[bb][(w * 16 + i_ * 8) * 64]), 16, 0, 0); \
      __builtin_amdgcn_global_load_lds(                                        \
        (const __attribute__((address_space(1))) void*)(gV0 + (size_t)(i_ * 8) * Tsz + kb_), \
        (__attribute__((address_space(3))) void*)(&Vt[bb][(w * 16 + i_ * 8) * 64]), 16, 0, 0); \
    }                                                                          \
  } while (0)
#else
#define STAGE(jj, bb) do {                                                     \
    const int kb_ = (jj) * 64;                                                 \
    _Pragma("unroll")                                                          \
    for (int cc_ = 0; cc_ < 2; ++cc_) {                                        \
      const int c_ = tid + cc_ * 256;                                          \
      const int rr_ = c_ >> 3, off_ = c_ & 7;                                  \
      const int dc_ = (off_ ^ (rr_ & 7)) << 3;                                 \
      *(uint4*)&Kl[bb][rr_ * 64 + dc_] =                                       \
          *(const uint4*)&Kg[(size_t)(kb_ + rr_) * Dh + off_ * 8];             \
      *(uint4*)&Vt[bb][rr_ * 64 + dc_] =                                       \
          *(const uint4*)&VTg[(size_t)rr_ * Tsz + kb_ + off_ * 8];             \
    }                                                                          \
  } while (0)
#endif

  for (int ph = 0; ph < 2; ++ph) {
    const int jq = ph ? (int)blockIdx.y : 31 - (int)blockIdx.y;

    // Q fragment (B-operand of S^T): lane holds Q[q=l15][d=quad*8+j].
    const int qrow = jq * 64 + w * 16 + l15;   // this lane's q (global row)
    const bf16x8 bq0 = *(const bf16x8*)&Q[(size_t)qrow * Dh + quad * 8];
    const bf16x8 bq1 = *(const bf16x8*)&Q[(size_t)qrow * Dh + 32 + quad * 8];

    f32x4 O[4];    // O^T: col q = l15, row d = nb*16 + quad*4 + r
#pragma unroll
    for (int nb = 0; nb < 4; ++nb) O[nb] = (f32x4){0.f, 0.f, 0.f, 0.f};
    float l_i = 0.f;               // per-lane partial sum (16 keys/lane/tile)

    STAGE(0, 0);

    for (int j = 0; j <= jq; ++j) {
      const int cur = j & 1;
      if (j < jq) {
        STAGE(j + 1, cur ^ 1);   // prefetch next tile (async DMA)
        asm volatile("s_waitcnt vmcnt(4)" ::: "memory");  // cur landed; 4 fly
      } else {
        asm volatile("s_waitcnt vmcnt(0)" ::: "memory");
      }
      BARRIER();

      const int kb = j * 64;
      const bool diag = (j == jq);
      const int tmax = diag ? (w + 1) : 4;   // 16-key sub-tiles with any work
      const u16* KT = Kl[cur];
      const u16* VL = Vt[cur];

      // S^T: A = K fragment (m=key=16t+l15, k=d=quad*8+jj), B = Q fragment.
      f32x4 S[4];
#pragma unroll
      for (int t = 0; t < 4; ++t) S[t] = (f32x4){0.f, 0.f, 0.f, 0.f};
      __builtin_amdgcn_s_setprio(1);
#pragma unroll
      for (int t = 0; t < 4; ++t) {
        if (t < tmax) {
          bf16x8 ak = *(const bf16x8*)&KT[(t * 16 + l15) * 64 + ((quad * 8) ^ cswz)];
          S[t] = __builtin_amdgcn_mfma_f32_16x16x32_bf16(ak, bq0, S[t], 0, 0, 0);
          ak = *(const bf16x8*)&KT[(t * 16 + l15) * 64 + ((quad * 8 + 32) ^ cswz)];
          S[t] = __builtin_amdgcn_mfma_f32_16x16x32_bf16(ak, bq1, S[t], 0, 0, 0);
        }
      }
      __builtin_amdgcn_s_setprio(0);

      // p = exp2(s) directly (scale pre-folded into Q); masked -> 0.
      float p[4][4];
      if (diag) {
#pragma unroll
        for (int t = 0; t < 4; ++t) {
          const int key0 = kb + t * 16 + quad * 4;
#pragma unroll
          for (int r = 0; r < 4; ++r) {
            const float sv =
                (t < tmax && key0 + r <= qrow) ? S[t][r] : NEG_BIG;
            p[t][r] = fast_exp2(sv);
            l_i += p[t][r];
          }
        }
      } else {
#pragma unroll
        for (int t = 0; t < 4; ++t)
#pragma unroll
          for (int r = 0; r < 4; ++r) {
            p[t][r] = fast_exp2(S[t][r]);
            l_i += p[t][r];
          }
      }

      // PV chunk 0 (keys 0..31 = tiles 0,1): B-frag key pi(quad*8+jj).
      u32x4 pu;
      pu[0] = pack2bf_trunc(p[0][0], p[0][1]);
      pu[1] = pack2bf_trunc(p[0][2], p[0][3]);
      pu[2] = pack2bf_trunc(p[1][0], p[1][1]);
      pu[3] = pack2bf_trunc(p[1][2], p[1][3]);
      bf16x8 pb = __builtin_bit_cast(bf16x8, pu);
      __builtin_amdgcn_s_setprio(1);
#pragma unroll
      for (int nb = 0; nb < 4; ++nb) {
        const uint2 a0 = *(const uint2*)&VL[(nb * 16 + l15) * 64 + ((quad * 4) ^ cswz)];
        const uint2 a1 = *(const uint2*)&VL[(nb * 16 + l15) * 64 + ((quad * 4 + 16) ^ cswz)];
        const u32x4 au = {a0.x, a0.y, a1.x, a1.y};
        O[nb] = __builtin_amdgcn_mfma_f32_16x16x32_bf16(
            __builtin_bit_cast(bf16x8, au), pb, O[nb], 0, 0, 0);
      }
      __builtin_amdgcn_s_setprio(0);
      if (tmax > 2) {   // PV chunk 1 (keys 32..63 = tiles 2,3)
        pu[0] = pack2bf_trunc(p[2][0], p[2][1]);
        pu[1] = pack2bf_trunc(p[2][2], p[2][3]);
        pu[2] = pack2bf_trunc(p[3][0], p[3][1]);
        pu[3] = pack2bf_trunc(p[3][2], p[3][3]);
        pb = __builtin_bit_cast(bf16x8, pu);
        __builtin_amdgcn_s_setprio(1);
#pragma unroll
        for (int nb = 0; nb < 4; ++nb) {
          const uint2 a0 = *(const uint2*)&VL[(nb * 16 + l15) * 64 + ((quad * 4 + 32) ^ cswz)];
          const uint2 a1 = *(const uint2*)&VL[(nb * 16 + l15) * 64 + ((quad * 4 + 48) ^ cswz)];
          const u32x4 au = {a0.x, a0.y, a1.x, a1.y};
          O[nb] = __builtin_amdgcn_mfma_f32_16x16x32_bf16(
              __builtin_bit_cast(bf16x8, au), pb, O[nb], 0, 0, 0);
        }
        __builtin_amdgcn_s_setprio(0);
      }
      BARRIER();   // all waves done reading buf[cur] before it is re-staged
    }

    // One cross-lane l reduction for the whole phase, then write out.
    float lt = l_i + __shfl_xor(l_i, 16, 64);
    lt += __shfl_xor(lt, 32, 64);
    const float inv = 1.0f / lt;
#pragma unroll
    for (int nb = 0; nb < 4; ++nb) {
      uint2 st;
      st.x = pack2bf(O[nb][0] * inv, O[nb][1] * inv);
      st.y = pack2bf(O[nb][2] * inv, O[nb][3] * inv);
      *(uint2*)&outp[(size_t)(b * Tsz + qrow) * Csz + h * Dh + nb * 16 + quad * 4] = st;
    }
  }
#undef STAGE
}

// ---------------------------------------------------------------------------
extern "C" void kernel_launch(void* const* d_in, const int* in_sizes, int n_in,
                              void* d_out, int out_size, void* d_ws, size_t ws_size,
                              hipStream_t stream) {
  const float* x      = (const float*)d_in[0];   // [B,T,C] fp32
  const float* W_attn = (const float*)d_in[1];   // [C,3C]  fp32
  const float* b_attn = (const float*)d_in[2];   // [3C]    fp32
  const float* W_proj = (const float*)d_in[3];   // [C,C]   fp32
  const float* b_proj = (const float*)d_in[4];   // [C]     fp32
  float* out = (float*)d_out;                    // [B,T,C] fp32

  u16* ws   = (u16*)d_ws;
  u16* xbf  = ws;                                // [B,T,C] bf16
  u16* qbuf = xbf  + (size_t)Mrows * Csz;        // [bh][t][d] (pre-scaled)
  u16* kbuf = qbuf + (size_t)Mrows * Csz;        // [bh][t][d]
  u16* vbuf = kbuf + (size_t)Mrows * Csz;        // [bh][d][t]  (transposed!)
  u16* aout = vbuf + (size_t)Mrows * Csz;        // [B,T,C] bf16
  u16* WTa  = aout + (size_t)Mrows * Csz;        // [3C][C] bf16
  u16* WTp  = WTa  + (size_t)Csz * 3 * Csz;      // [C][C]  bf16

  prep<<<CVT_BLKS + TRA_BLKS + TRP_BLKS, 256, 0, stream>>>(
      x, xbf, W_attn, WTa, W_proj, WTp);
  // 128x128 tile, 256 thr: grid 24x64 = 1536 blocks, 3 blocks/CU.
  gemm_bt<0><<<dim3(3 * Csz / 128, Mrows / 128), dim3(256), 0, stream>>>(
      xbf, WTa, b_attn, qbuf, kbuf, vbuf, nullptr, 3 * Csz);
  attn_fused<<<dim3(Bsz * Hn, Tsz / 128), 256, 0, stream>>>(
      qbuf, kbuf, vbuf, aout);
  // 128x128 tile, 256 thr: grid 8x64 = 512 blocks.
  gemm_bt<1><<<dim3(Csz / 128, Mrows / 128), dim3(256), 0, stream>>>(
      aout, WTp, b_proj, nullptr, nullptr, nullptr, out, Csz);
}